// Round 14
// baseline (565.874 us; speedup 1.0000x reference)
//
#include <hip/hip_runtime.h>
#include <math.h>

// ---------------------------------------------------------------------------
// GCN 3-layer forward: h = A_norm @ (h @ W) + b  (x3, relu between)
//   h intermediates stored SLICE-MAJOR: [8][n][32] f16 (slice = 64B of row).
//   Aggregation: slice-sliced — block handles ONE slice for 8 nodes;
//     slice = blockIdx & 7 -> with round-robin block->XCD dispatch, XCD k
//     only touches slice k (3.2 MB, L2-resident) -> gather misses become
//     compulsory-only (~26 MB vs 191 MB replication floor).
//   GEMM: round-12 structure (128x256 full-N tile, 512 thr, BK=32, dbuf +
//     vmcnt(5)); A staged from slice-major (K-step == one slice), epilogue
//     writes slice-major. W pre-split f16 hi/lo (C = A@Wh + A@Wl).
//   Round-13 fusion REVERTED (1 blk/CU killed gather TLP: 169µs, 17% occ).
// ---------------------------------------------------------------------------

using f16x8   = __attribute__((ext_vector_type(8))) _Float16;
using ushort4v = __attribute__((ext_vector_type(4))) unsigned short;
using f32x4   = __attribute__((ext_vector_type(4))) float;

__device__ inline unsigned short f2h_bits(float v) {
    _Float16 h = (_Float16)v;
    union { _Float16 h; unsigned short u; } c; c.h = h;
    return c.u;
}

// ---------------------------------------------------------------------------
// prep kernels
// ---------------------------------------------------------------------------

__global__ void hist_kernel(const int* __restrict__ dst, int E, int* __restrict__ cnt) {
    int e = blockIdx.x * blockDim.x + threadIdx.x;
    if (e < E) atomicAdd(&cnt[dst[e]], 1);
}

__global__ void scan_block_kernel(const int* __restrict__ in, int n,
                                  int* __restrict__ out, int* __restrict__ bsums) {
    __shared__ int s[256];
    int t = threadIdx.x;
    int i = blockIdx.x * 256 + t;
    s[t] = (i < n) ? in[i] : 0;
    __syncthreads();
    for (int off = 1; off < 256; off <<= 1) {
        int addv = (t >= off) ? s[t - off] : 0;
        __syncthreads();
        s[t] += addv;
        __syncthreads();
    }
    if (i < n) out[i] = s[t];
    if (t == 255) bsums[blockIdx.x] = s[255];
}

__global__ void scan_sums_kernel(int* __restrict__ bsums, int nb) {
    __shared__ int s[256];
    int t = threadIdx.x;
    s[t] = (t < nb) ? bsums[t] : 0;
    __syncthreads();
    for (int off = 1; off < 256; off <<= 1) {
        int addv = (t >= off) ? s[t - off] : 0;
        __syncthreads();
        s[t] += addv;
        __syncthreads();
    }
    if (t < nb) bsums[t] = s[t];
}

__global__ void scan_add_dinv_kernel(int* __restrict__ scn, int n, const int* __restrict__ bsums,
                                     const int* __restrict__ cnt, float* __restrict__ dinv,
                                     int* __restrict__ cursor) {
    int i = blockIdx.x * 256 + threadIdx.x;
    if (i < n) {
        int s = scn[i] + (blockIdx.x > 0 ? bsums[blockIdx.x - 1] : 0);
        scn[i] = s;
        int c = cnt[i];
        dinv[i] = rsqrtf((float)(c + 1));
        cursor[i] = s - c;
    }
}

__global__ void scatter_kernel(const int* __restrict__ src, const int* __restrict__ dst, int E,
                               const float* __restrict__ dinv, int* __restrict__ cursor,
                               int* __restrict__ ssrc, float* __restrict__ snorm) {
    int e = blockIdx.x * blockDim.x + threadIdx.x;
    if (e < E) {
        int s = src[e], d0 = dst[e];
        int pos = atomicAdd(&cursor[d0], 1);
        ssrc[pos] = s;
        snorm[pos] = dinv[s] * dinv[d0];
    }
}

// 3 weights fused: W [k][n] f32 -> Wsp[w] = {hi,lo} [n][k] f16, LDS transpose
__global__ __launch_bounds__(256) void wsplit3_kernel(const float* __restrict__ Wa,
                                                      const float* __restrict__ Wb,
                                                      const float* __restrict__ Wc,
                                                      unsigned short* __restrict__ Wsp) {
    __shared__ float t[64][65];
    int w = blockIdx.z;
    const float* W = (w == 0) ? Wa : (w == 1) ? Wb : Wc;
    int k0 = blockIdx.x * 64, n0 = blockIdx.y * 64;
    int tid = threadIdx.x;
    int r = tid >> 6, c = tid & 63;
#pragma unroll
    for (int i = 0; i < 16; ++i) {
        int kk = i * 4 + r;
        t[kk][c] = W[(size_t)(k0 + kk) * 256 + n0 + c];
    }
    __syncthreads();
    unsigned short* Hi = Wsp + (size_t)w * 131072;
    unsigned short* Lo = Hi + 65536;
#pragma unroll
    for (int i = 0; i < 16; ++i) {
        int nn = i * 4 + r;
        float v = t[c][nn];
        _Float16 hh = (_Float16)v;
        float rr = v - (float)hh;
        _Float16 ll = (_Float16)rr;
        union { _Float16 h; unsigned short u; } ch, cl; ch.h = hh; cl.h = ll;
        Hi[(size_t)(n0 + nn) * 256 + k0 + c] = ch.u;
        Lo[(size_t)(n0 + nn) * 256 + k0 + c] = cl.u;
    }
}

// x f32 -> f16 slice-major [8][n][32]
__global__ void xcast8_kernel(const float* __restrict__ in, unsigned short* __restrict__ out16,
                              int n, int total4) {
    int i = blockIdx.x * blockDim.x + threadIdx.x;
    int stride = gridDim.x * blockDim.x;
    for (; i < total4; i += stride) {
        float4 v = ((const float4*)in)[i];
        ushort4v o;
        o[0] = f2h_bits(v.x); o[1] = f2h_bits(v.y);
        o[2] = f2h_bits(v.z); o[3] = f2h_bits(v.w);
        int nd = i >> 6;              // node (64 float4s per node)
        int f  = (i & 63) * 4;        // feature 0..252
        size_t off = (size_t)(f >> 5) * n * 32 + (size_t)nd * 32 + (f & 31);
        *(ushort4v*)(out16 + off) = o;
    }
}

// ---------------------------------------------------------------------------
// f16 MFMA GEMM, tile 128x256 (full N), 512 threads / 8 waves (2x4), BK=32,
// 2-buffer + vmcnt(5). A is SLICE-MAJOR [8][M][32] f16 (K-step == slice k);
// W row-major [n][k] pre-split hi/lo. C written slice-major [8][M][32] f16.
// Per-lane source pre-permuted with inverse of read swizzle
// swaddr(a)=a^(((a>>6)&7)<<4)  (inverse: a4=d4^d6^d8, a5=d5^d7, a6=d6^d8)
// ---------------------------------------------------------------------------
__global__ __launch_bounds__(512) void gemm_f16_kernel(
        const unsigned short* __restrict__ Af, const unsigned short* __restrict__ Whf,
        const unsigned short* __restrict__ Wlf, unsigned short* __restrict__ C16, int M) {
    __shared__ unsigned short lds[40960];  // 80KB: 2 x {A 4096 | Wh 8192 | Wl 8192}

    const int tid  = threadIdx.x;
    const int lane = tid & 63;
    const int wid  = tid >> 6;
    const int wr   = wid >> 2;
    const int wc   = wid & 3;
    const int mBase = blockIdx.x * 128;

    const int b0 = (lane ^ (lane >> 2) ^ (lane >> 4)) & 1;
    const int b1 = ((lane >> 1) ^ (lane >> 3)) & 1;
    const int b2 = ((lane >> 2) ^ (lane >> 4)) & 1;
    const int g  = (lane & 0x38) | (b2 << 2) | (b1 << 1) | b0;
    const int srow = g >> 2;   // row within 16-row chunk
    const int skg  = g & 3;    // 16B granule within 64B row-slice

    // wave's 5 stage chunks; A chunks advance by n*32 per k, W by 32.
    const unsigned short* cptr[5];
    size_t kmul[5];
    int cdst[5];
#pragma unroll
    for (int i = 0; i < 5; ++i) {
        int c = wid * 5 + i;
        if (c < 8) {
            int row = mBase + c * 16 + srow;
            if (row >= M) row = M - 1;   // clamped rows never stored
            cptr[i] = Af + (size_t)row * 32 + skg * 8;   // slice-major: +k*M*32
            kmul[i] = (size_t)M * 32;
            cdst[i] = c * 512;
        } else if (c < 24) {
            int row = (c - 8) * 16 + srow;
            cptr[i] = Whf + (size_t)row * 256 + skg * 8;
            kmul[i] = 32;
            cdst[i] = 4096 + (c - 8) * 512;
        } else {
            int row = (c - 24) * 16 + srow;
            cptr[i] = Wlf + (size_t)row * 256 + skg * 8;
            kmul[i] = 32;
            cdst[i] = 12288 + (c - 24) * 512;
        }
    }

    f32x4 acc[4][4];
#pragma unroll
    for (int i = 0; i < 4; ++i)
#pragma unroll
        for (int j = 0; j < 4; ++j) acc[i][j] = (f32x4){0.f, 0.f, 0.f, 0.f};

    auto stage = [&](int p, int k) {
        unsigned short* dbase = lds + p * 20480;
#pragma unroll
        for (int i = 0; i < 5; ++i) {
            __builtin_amdgcn_global_load_lds(
                (const __attribute__((address_space(1))) void*)(cptr[i] + (size_t)k * kmul[i]),
                (__attribute__((address_space(3))) void*)(dbase + cdst[i]),
                16, 0, 0);
        }
    };

    stage(0, 0);

#pragma unroll
    for (int k = 0; k < 8; ++k) {
        const int p = k & 1;
        if (k < 7) {
            stage(p ^ 1, k + 1);
            asm volatile("s_waitcnt vmcnt(5)" ::: "memory");
        } else {
            asm volatile("s_waitcnt vmcnt(0)" ::: "memory");
        }
        __builtin_amdgcn_s_barrier();

        const unsigned short* As = lds + p * 20480;
        const unsigned short* Bh = As + 4096;
        const unsigned short* Bl = As + 12288;

        const int kb = (lane >> 4) * 8;
        f16x8 fa[4], fbh[4], fbl[4];
#pragma unroll
        for (int mi = 0; mi < 4; ++mi) {
            int row = wr * 64 + mi * 16 + (lane & 15);
            int off = (row * 64 + kb * 2) ^ ((row & 7) << 4);
            fa[mi] = *(const f16x8*)((const char*)As + off);
        }
#pragma unroll
        for (int ni = 0; ni < 4; ++ni) {
            int col = wc * 64 + ni * 16 + (lane & 15);
            int off = (col * 64 + kb * 2) ^ ((col & 7) << 4);
            fbh[ni] = *(const f16x8*)((const char*)Bh + off);
            fbl[ni] = *(const f16x8*)((const char*)Bl + off);
        }
#pragma unroll
        for (int mi = 0; mi < 4; ++mi)
#pragma unroll
            for (int ni = 0; ni < 4; ++ni) {
                acc[mi][ni] = __builtin_amdgcn_mfma_f32_16x16x32_f16(
                    fa[mi], fbh[ni], acc[mi][ni], 0, 0, 0);
                acc[mi][ni] = __builtin_amdgcn_mfma_f32_16x16x32_f16(
                    fa[mi], fbl[ni], acc[mi][ni], 0, 0, 0);
            }
        __builtin_amdgcn_s_barrier();
    }

    // epilogue: f16 store, SLICE-MAJOR: off = (col>>5)*M*32 + row*32 + (col&31)
#pragma unroll
    for (int mi = 0; mi < 4; ++mi) {
        int row0 = mBase + wr * 64 + mi * 16 + (lane >> 4) * 4;
#pragma unroll
        for (int ni = 0; ni < 4; ++ni) {
            int col = wc * 64 + ni * 16 + (lane & 15);
            size_t sbase = (size_t)(col >> 5) * M * 32 + (col & 31);
#pragma unroll
            for (int r = 0; r < 4; ++r) {
                int row = row0 + r;
                if (row < M) C16[sbase + (size_t)row * 32] = f2h_bits(acc[mi][ni][r]);
            }
        }
    }
}

// ---------------------------------------------------------------------------
// slice-sliced aggregation: block = ONE slice (32 feats) x 8 nodes.
// slice = blockIdx & 7  (round-robin dispatch -> XCD k handles slice k only;
// its 3.2MB slice region becomes L2-resident). 4 waves x 2 nodes; lane
// handles 1 feature (2B gather per edge). f32 accumulate; j ascending ->
// per-(node,feat) accumulation order identical to round 8 (bit-identical).
// SPLIT=1: emit f16 slice-major.  SPLIT=0: emit f32 row-major (final).
// ---------------------------------------------------------------------------
template <int RELU, int SPLIT>
__global__ __launch_bounds__(256) void agg8_kernel(const unsigned short* __restrict__ hH,
                                                   const int* __restrict__ ssrc,
                                                   const float* __restrict__ snorm,
                                                   const int* __restrict__ cnt,
                                                   const int* __restrict__ scanv,
                                                   const float* __restrict__ dinv,
                                                   const float* __restrict__ bias,
                                                   unsigned short* __restrict__ outH,
                                                   float* __restrict__ outF, int n) {
    const int slice = blockIdx.x & 7;
    const int quad  = blockIdx.x >> 3;
    const int tid   = threadIdx.x;
    const int node  = quad * 8 + (tid >> 6) * 2 + ((tid >> 5) & 1);
    const int l32   = tid & 31;
    if (node >= n) return;

    const _Float16* hf = (const _Float16*)hH;
    const size_t sbase = (size_t)slice * n * 32;

    int end = scanv[node];
    int start = end - cnt[node];
    float di = dinv[node];
    float wself = di * di;

    float acc = (float)hf[sbase + (size_t)node * 32 + l32] * wself;

    int j = start;
    for (; j + 4 <= end; j += 4) {
        int s0 = ssrc[j], s1 = ssrc[j + 1], s2 = ssrc[j + 2], s3 = ssrc[j + 3];
        float w0 = snorm[j], w1 = snorm[j + 1], w2 = snorm[j + 2], w3 = snorm[j + 3];
        float u0 = (float)hf[sbase + (size_t)s0 * 32 + l32];
        float u1 = (float)hf[sbase + (size_t)s1 * 32 + l32];
        float u2 = (float)hf[sbase + (size_t)s2 * 32 + l32];
        float u3 = (float)hf[sbase + (size_t)s3 * 32 + l32];
        acc = fmaf(u0, w0, acc);
        acc = fmaf(u1, w1, acc);
        acc = fmaf(u2, w2, acc);
        acc = fmaf(u3, w3, acc);
    }
    for (; j < end; ++j) {
        int s = ssrc[j];
        float wn = snorm[j];
        acc = fmaf((float)hf[sbase + (size_t)s * 32 + l32], wn, acc);
    }

    acc += bias[slice * 32 + l32];
    if (RELU) acc = fmaxf(acc, 0.0f);
    if (SPLIT) {
        outH[sbase + (size_t)node * 32 + l32] = f2h_bits(acc);
    } else {
        outF[(size_t)node * 256 + slice * 32 + l32] = acc;
    }
}

extern "C" void kernel_launch(void* const* d_in, const int* in_sizes, int n_in,
                              void* d_out, int out_size, void* d_ws, size_t ws_size,
                              hipStream_t stream) {
    const float* x  = (const float*)d_in[0];
    const int*   ei = (const int*)d_in[1];
    const float* W1 = (const float*)d_in[2];
    const float* b1 = (const float*)d_in[3];
    const float* W2 = (const float*)d_in[4];
    const float* b2 = (const float*)d_in[5];
    const float* W3 = (const float*)d_in[6];
    const float* b3 = (const float*)d_in[7];

    const int n = in_sizes[0] / 256;  // 50000
    const int E = in_sizes[1] / 2;    // 800000
    const int* src = ei;
    const int* dst = ei + E;

    // d_out as f16 scratch: [hAct | xF16], each n*256 f16 (== out_size f32 bytes)
    unsigned short* hAct = (unsigned short*)d_out;
    unsigned short* xF   = hAct + (size_t)n * 256;
    float* outF = (float*)d_out;

    char* ws = (char*)d_ws;
    unsigned short* hLin = (unsigned short*)ws;    // n*256 f16 (25.6 MB)
    size_t off  = (size_t)n * 256 * 2;
    off = (off + 255) & ~(size_t)255;
    float* dinv = (float*)(ws + off); off += (size_t)n * 4;
    int*   cnt  = (int*)(ws + off);   off += (size_t)n * 4;
    int*   scn  = (int*)(ws + off);   off += (size_t)n * 4;
    int*   cur  = (int*)(ws + off);   off += (size_t)n * 4;
    int*   bsum = (int*)(ws + off);   off += 4096;
    int*   ssrc = (int*)(ws + off);   off += (size_t)E * 4;
    float* snrm = (float*)(ws + off); off += (size_t)E * 4;
    off = (off + 255) & ~(size_t)255;
    unsigned short* Wsp = (unsigned short*)(ws + off);  // [3][2][256][256] f16
    off += (size_t)3 * 2 * 65536 * 2;

    hipMemsetAsync(cnt, 0, (size_t)n * 4, stream);

    const int eb = (E + 255) / 256;
    const int nb = (n + 255) / 256;  // 196 <= 256 required by scan_sums

    wsplit3_kernel<<<dim3(4, 4, 3), 256, 0, stream>>>(W1, W2, W3, Wsp);
    xcast8_kernel<<<2048, 256, 0, stream>>>(x, xF, n, n * 64);

    hist_kernel<<<eb, 256, 0, stream>>>(dst, E, cnt);
    scan_block_kernel<<<nb, 256, 0, stream>>>(cnt, n, scn, bsum);
    scan_sums_kernel<<<1, 256, 0, stream>>>(bsum, nb);
    scan_add_dinv_kernel<<<nb, 256, 0, stream>>>(scn, n, bsum, cnt, dinv, cur);
    scatter_kernel<<<eb, 256, 0, stream>>>(src, dst, E, dinv, cur, ssrc, snrm);

    const int gb = (n + 127) / 128;        // 391 M-tile blocks
    const int ag = ((n + 7) / 8) * 8;      // 6250 quads x 8 slices = 50000 blocks

    gemm_f16_kernel<<<gb, 512, 0, stream>>>(xF, Wsp, Wsp + 65536, hLin, n);
    agg8_kernel<1, 1><<<ag, 256, 0, stream>>>(hLin, ssrc, snrm, cnt, scn, dinv, b1,
                                              hAct, nullptr, n);
    gemm_f16_kernel<<<gb, 512, 0, stream>>>(hAct, Wsp + 131072, Wsp + 196608, hLin, n);
    agg8_kernel<1, 1><<<ag, 256, 0, stream>>>(hLin, ssrc, snrm, cnt, scn, dinv, b2,
                                              hAct, nullptr, n);
    gemm_f16_kernel<<<gb, 512, 0, stream>>>(hAct, Wsp + 262144, Wsp + 327680, hLin, n);
    agg8_kernel<0, 0><<<ag, 256, 0, stream>>>(hLin, ssrc, snrm, cnt, scn, dinv, b3,
                                              nullptr, outF, n);
}

// Round 15
// 349.955 us; speedup vs baseline: 1.6170x; 1.6170x over previous
//
#include <hip/hip_runtime.h>
#include <math.h>

// ---------------------------------------------------------------------------
// GCN 3-layer forward: h = A_norm @ (h @ W) + b  (x3, relu between)
//   ROUND-8 CONFIG RESTORED (best measured: 355.1 µs):
//   GEMM: f16 MFMA, A = fp16, W pre-split f16 hi/lo: C = A@Wh + A@Wl.
//         128x128 tile, BK=32, dbuf LDS (2x24KB) + vmcnt(6) + raw barriers,
//         XCD-paired bijective block swizzle, 782 blocks x 256 thr.
//   Agg:  one wave per node, full 512B-row half4 gathers, f32 accum.
//         At the beyond-L2 ceiling: FETCH 191MB = 8-XCD x 25.6MB compulsory
//         replication, moving at the observed ~3.9 TB/s fabric rate.
//         (2-pass split and slice-major variants both measured worse.)
//   Prep consolidation (this round's only change): wsplit3+xcast merged into
//         prep_wx_kernel; scan_sums folded into scan_add_dinv (block-reduce
//         of 196 partial sums in LDS). 14 -> 12 dispatches.
// ---------------------------------------------------------------------------

using f16x8   = __attribute__((ext_vector_type(8))) _Float16;
using ushort4v = __attribute__((ext_vector_type(4))) unsigned short;
using f32x4   = __attribute__((ext_vector_type(4))) float;
using half4   = __attribute__((ext_vector_type(4))) _Float16;

__device__ inline unsigned short f2h_bits(float v) {
    _Float16 h = (_Float16)v;
    union { _Float16 h; unsigned short u; } c; c.h = h;
    return c.u;
}

// ---------------------------------------------------------------------------
// prep kernels
// ---------------------------------------------------------------------------

__global__ void hist_kernel(const int* __restrict__ dst, int E, int* __restrict__ cnt) {
    int e = blockIdx.x * blockDim.x + threadIdx.x;
    if (e < E) atomicAdd(&cnt[dst[e]], 1);
}

__global__ void scan_block_kernel(const int* __restrict__ in, int n,
                                  int* __restrict__ out, int* __restrict__ bsums) {
    __shared__ int s[256];
    int t = threadIdx.x;
    int i = blockIdx.x * 256 + t;
    s[t] = (i < n) ? in[i] : 0;
    __syncthreads();
    for (int off = 1; off < 256; off <<= 1) {
        int addv = (t >= off) ? s[t - off] : 0;
        __syncthreads();
        s[t] += addv;
        __syncthreads();
    }
    if (i < n) out[i] = s[t];
    if (t == 255) bsums[blockIdx.x] = s[255];
}

// scan finalize + dinv + cursor; block b computes prefix = sum(bsums[0..b-1])
// internally (196 partials, LDS tree reduce) -> scan_sums kernel eliminated.
__global__ void scan_add_dinv_kernel(int* __restrict__ scn, int n,
                                     const int* __restrict__ bsums, int nbv,
                                     const int* __restrict__ cnt, float* __restrict__ dinv,
                                     int* __restrict__ cursor) {
    __shared__ int sred[256];
    int t = threadIdx.x;
    int b = blockIdx.x;
    sred[t] = (t < b && t < nbv) ? bsums[t] : 0;
    __syncthreads();
    for (int off = 128; off > 0; off >>= 1) {
        if (t < off) sred[t] += sred[t + off];
        __syncthreads();
    }
    int prefix = sred[0];
    int i = b * 256 + t;
    if (i < n) {
        int s = scn[i] + prefix;
        scn[i] = s;
        int c = cnt[i];
        dinv[i] = rsqrtf((float)(c + 1));
        cursor[i] = s - c;
    }
}

__global__ void scatter_kernel(const int* __restrict__ src, const int* __restrict__ dst, int E,
                               const float* __restrict__ dinv, int* __restrict__ cursor,
                               int* __restrict__ ssrc, float* __restrict__ snorm) {
    int e = blockIdx.x * blockDim.x + threadIdx.x;
    if (e < E) {
        int s = src[e], d0 = dst[e];
        int pos = atomicAdd(&cursor[d0], 1);
        ssrc[pos] = s;
        snorm[pos] = dinv[s] * dinv[d0];
    }
}

// merged: blocks [0,48) = wsplit tiles (3 weights x 4x4 64-tiles);
//         blocks [48,..) = xcast grid-stride. Branch is block-uniform.
__global__ __launch_bounds__(256) void prep_wx_kernel(
        const float* __restrict__ Wa, const float* __restrict__ Wb,
        const float* __restrict__ Wc, unsigned short* __restrict__ Wsp,
        const float* __restrict__ x, unsigned short* __restrict__ xF, int total4) {
    __shared__ float t[64][65];
    const int bid = blockIdx.x;
    const int tid = threadIdx.x;
    if (bid < 48) {
        int w = bid >> 4;                     // weight 0..2
        int k0 = ((bid >> 2) & 3) * 64;
        int n0 = (bid & 3) * 64;
        const float* W = (w == 0) ? Wa : (w == 1) ? Wb : Wc;
        int r = tid >> 6, c = tid & 63;
#pragma unroll
        for (int i = 0; i < 16; ++i) {
            int kk = i * 4 + r;
            t[kk][c] = W[(size_t)(k0 + kk) * 256 + n0 + c];
        }
        __syncthreads();
        unsigned short* Hi = Wsp + (size_t)w * 131072;
        unsigned short* Lo = Hi + 65536;
#pragma unroll
        for (int i = 0; i < 16; ++i) {
            int nn = i * 4 + r;
            float v = t[c][nn];
            _Float16 hh = (_Float16)v;
            float rr = v - (float)hh;
            _Float16 ll = (_Float16)rr;
            union { _Float16 h; unsigned short u; } ch, cl; ch.h = hh; cl.h = ll;
            Hi[(size_t)(n0 + nn) * 256 + k0 + c] = ch.u;
            Lo[(size_t)(n0 + nn) * 256 + k0 + c] = cl.u;
        }
    } else {
        int i = (bid - 48) * 256 + tid;
        int stride = (gridDim.x - 48) * 256;
        for (; i < total4; i += stride) {
            float4 v = ((const float4*)x)[i];
            ushort4v o;
            o[0] = f2h_bits(v.x); o[1] = f2h_bits(v.y);
            o[2] = f2h_bits(v.z); o[3] = f2h_bits(v.w);
            ((ushort4v*)xF)[i] = o;
        }
    }
}

// ---------------------------------------------------------------------------
// f16 MFMA GEMM (round-8 version): 128x128 tile, BK=32, 256 thr / 4 waves,
// 2-buffer LDS + vmcnt(6) + raw barriers, XCD-paired bijective swizzle.
// Per-lane global source pre-permuted with the inverse of the read swizzle
// swaddr(a) = a ^ (((a>>6)&7)<<4)  (inverse: a4=d4^d6^d8, a5=d5^d7, a6=d6^d8)
// ---------------------------------------------------------------------------
__global__ __launch_bounds__(256) void gemm_f16_kernel(
        const unsigned short* __restrict__ Af, const unsigned short* __restrict__ Whf,
        const unsigned short* __restrict__ Wlf, unsigned short* __restrict__ C16, int M) {
    __shared__ unsigned short lds[24576];  // 48KB: 2 x {A|Wh|Wl, 4096 ushorts each}

    const int tid  = threadIdx.x;
    const int lane = tid & 63;
    const int wid  = tid >> 6;
    const int wr   = wid >> 1, wc = wid & 1;

    // XCD-paired bijective swizzle over 782 blocks (8 XCDs: 6x98 + 2x97)
    const int orig = blockIdx.x;
    const int xcd  = orig & 7;
    const int idx  = orig >> 3;
    const int wg   = (xcd < 6 ? xcd * 98 : 588 + (xcd - 6) * 97) + idx;
    const int mBase = (wg >> 1) * 128;
    const int nBase = (wg & 1) * 128;

    const int b0 = (lane ^ (lane >> 2) ^ (lane >> 4)) & 1;
    const int b1 = ((lane >> 1) ^ (lane >> 3)) & 1;
    const int b2 = ((lane >> 2) ^ (lane >> 4)) & 1;
    const int g  = (lane & 0x38) | (b2 << 2) | (b1 << 1) | b0;
    const int srow = g >> 2;   // row within 16-row chunk
    const int skg  = g & 3;    // 16B granule within 64B row-slice

    // this wave's 6 stage chunks: c = wid*6 + i; array a = c>>3 (0:A 1:Wh 2:Wl)
    const unsigned short* cptr[6];
    int cdst[6];
#pragma unroll
    for (int i = 0; i < 6; ++i) {
        int c = wid * 6 + i;
        int a = c >> 3;
        int s = c & 7;
        const unsigned short* base = (a == 0) ? Af : (a == 1) ? Whf : Wlf;
        int rb = (a == 0) ? mBase : nBase;
        int r = rb + s * 16 + srow;
        if (a == 0 && r >= M) r = M - 1;  // clamped rows never stored
        cptr[i] = base + (size_t)r * 256 + skg * 8;
        cdst[i] = a * 4096 + s * 512;
    }

    f32x4 acc[4][4];
#pragma unroll
    for (int i = 0; i < 4; ++i)
#pragma unroll
        for (int j = 0; j < 4; ++j) acc[i][j] = (f32x4){0.f, 0.f, 0.f, 0.f};

    auto stage = [&](int p, int k) {
        unsigned short* dbase = lds + p * 12288;
        const int k0 = k * 32;
#pragma unroll
        for (int i = 0; i < 6; ++i) {
            __builtin_amdgcn_global_load_lds(
                (const __attribute__((address_space(1))) void*)(cptr[i] + k0),
                (__attribute__((address_space(3))) void*)(dbase + cdst[i]),
                16, 0, 0);
        }
    };

    stage(0, 0);  // prologue

#pragma unroll
    for (int k = 0; k < 8; ++k) {
        const int p = k & 1;
        if (k < 7) {
            stage(p ^ 1, k + 1);
            asm volatile("s_waitcnt vmcnt(6)" ::: "memory");  // prev stage landed
        } else {
            asm volatile("s_waitcnt vmcnt(0)" ::: "memory");
        }
        __builtin_amdgcn_s_barrier();  // all waves' buf[p] ready

        const unsigned short* As = lds + p * 12288;
        const unsigned short* Bh = As + 4096;
        const unsigned short* Bl = As + 8192;

        const int kb = (lane >> 4) * 8;
        f16x8 fa[4], fbh[4], fbl[4];
#pragma unroll
        for (int mi = 0; mi < 4; ++mi) {
            int row = wr * 64 + mi * 16 + (lane & 15);
            int off = (row * 64 + kb * 2) ^ ((row & 7) << 4);
            fa[mi] = *(const f16x8*)((const char*)As + off);
        }
#pragma unroll
        for (int ni = 0; ni < 4; ++ni) {
            int col = wc * 64 + ni * 16 + (lane & 15);
            int off = (col * 64 + kb * 2) ^ ((col & 7) << 4);
            fbh[ni] = *(const f16x8*)((const char*)Bh + off);
            fbl[ni] = *(const f16x8*)((const char*)Bl + off);
        }
#pragma unroll
        for (int mi = 0; mi < 4; ++mi)
#pragma unroll
            for (int ni = 0; ni < 4; ++ni) {
                acc[mi][ni] = __builtin_amdgcn_mfma_f32_16x16x32_f16(
                    fa[mi], fbh[ni], acc[mi][ni], 0, 0, 0);
                acc[mi][ni] = __builtin_amdgcn_mfma_f32_16x16x32_f16(
                    fa[mi], fbl[ni], acc[mi][ni], 0, 0, 0);
            }
        __builtin_amdgcn_s_barrier();  // reads done before buf[p] is restaged
    }

    // epilogue: f16 store. C row = (lane>>4)*4 + r, col = lane&15 per frag
#pragma unroll
    for (int mi = 0; mi < 4; ++mi) {
        int row0 = mBase + wr * 64 + mi * 16 + (lane >> 4) * 4;
#pragma unroll
        for (int ni = 0; ni < 4; ++ni) {
            int col = nBase + wc * 64 + ni * 16 + (lane & 15);
#pragma unroll
            for (int r = 0; r < 4; ++r) {
                int row = row0 + r;
                if (row < M) C16[(size_t)row * 256 + col] = f2h_bits(acc[mi][ni][r]);
            }
        }
    }
}

// ---------------------------------------------------------------------------
// aggregation (round-8 version): one 64-lane wave per node; fp16 gather
// (half4, full 512B row), f32 accumulate.
// SPLIT=1: emit f16 h (next GEMM's A).  SPLIT=0: emit f32 (final out).
// ---------------------------------------------------------------------------
template <int RELU, int SPLIT>
__global__ __launch_bounds__(256) void agg_kernel(const unsigned short* __restrict__ hH,
                                                  const int* __restrict__ ssrc,
                                                  const float* __restrict__ snorm,
                                                  const int* __restrict__ cnt,
                                                  const int* __restrict__ scanv,
                                                  const float* __restrict__ dinv,
                                                  const float* __restrict__ bias,
                                                  unsigned short* __restrict__ outH,
                                                  float* __restrict__ outF, int n) {
    int node = blockIdx.x * 4 + (threadIdx.x >> 6);
    int lane = threadIdx.x & 63;
    if (node >= n) return;
    int end = scanv[node];
    int start = end - cnt[node];
    float di = dinv[node];
    float wself = di * di;

    half4 v = ((const half4*)(hH + (size_t)node * 256))[lane];
    float ax = (float)v[0] * wself, ay = (float)v[1] * wself;
    float az = (float)v[2] * wself, aw = (float)v[3] * wself;

    int j = start;
    for (; j + 4 <= end; j += 4) {
        int s0 = ssrc[j], s1 = ssrc[j + 1], s2 = ssrc[j + 2], s3 = ssrc[j + 3];
        float w0 = snorm[j], w1 = snorm[j + 1], w2 = snorm[j + 2], w3 = snorm[j + 3];
        half4 u0 = ((const half4*)(hH + (size_t)s0 * 256))[lane];
        half4 u1 = ((const half4*)(hH + (size_t)s1 * 256))[lane];
        half4 u2 = ((const half4*)(hH + (size_t)s2 * 256))[lane];
        half4 u3 = ((const half4*)(hH + (size_t)s3 * 256))[lane];
        ax = fmaf((float)u0[0], w0, ax); ay = fmaf((float)u0[1], w0, ay);
        az = fmaf((float)u0[2], w0, az); aw = fmaf((float)u0[3], w0, aw);
        ax = fmaf((float)u1[0], w1, ax); ay = fmaf((float)u1[1], w1, ay);
        az = fmaf((float)u1[2], w1, az); aw = fmaf((float)u1[3], w1, aw);
        ax = fmaf((float)u2[0], w2, ax); ay = fmaf((float)u2[1], w2, ay);
        az = fmaf((float)u2[2], w2, az); aw = fmaf((float)u2[3], w2, aw);
        ax = fmaf((float)u3[0], w3, ax); ay = fmaf((float)u3[1], w3, ay);
        az = fmaf((float)u3[2], w3, az); aw = fmaf((float)u3[3], w3, aw);
    }
    for (; j < end; ++j) {
        int s = ssrc[j];
        float wn = snorm[j];
        half4 u = ((const half4*)(hH + (size_t)s * 256))[lane];
        ax = fmaf((float)u[0], wn, ax); ay = fmaf((float)u[1], wn, ay);
        az = fmaf((float)u[2], wn, az); aw = fmaf((float)u[3], wn, aw);
    }

    float4 bb = ((const float4*)bias)[lane];
    ax += bb.x; ay += bb.y; az += bb.z; aw += bb.w;
    if (RELU) {
        ax = fmaxf(ax, 0.0f); ay = fmaxf(ay, 0.0f);
        az = fmaxf(az, 0.0f); aw = fmaxf(aw, 0.0f);
    }
    if (SPLIT) {
        ushort4v o;
        o[0] = f2h_bits(ax); o[1] = f2h_bits(ay);
        o[2] = f2h_bits(az); o[3] = f2h_bits(aw);
        ((ushort4v*)(outH + (size_t)node * 256))[lane] = o;
    } else {
        float4 o = {ax, ay, az, aw};
        ((float4*)(outF + (size_t)node * 256))[lane] = o;
    }
}

extern "C" void kernel_launch(void* const* d_in, const int* in_sizes, int n_in,
                              void* d_out, int out_size, void* d_ws, size_t ws_size,
                              hipStream_t stream) {
    const float* x  = (const float*)d_in[0];
    const int*   ei = (const int*)d_in[1];
    const float* W1 = (const float*)d_in[2];
    const float* b1 = (const float*)d_in[3];
    const float* W2 = (const float*)d_in[4];
    const float* b2 = (const float*)d_in[5];
    const float* W3 = (const float*)d_in[6];
    const float* b3 = (const float*)d_in[7];

    const int n = in_sizes[0] / 256;  // 50000
    const int E = in_sizes[1] / 2;    // 800000
    const int* src = ei;
    const int* dst = ei + E;

    // d_out as f16 scratch: [hAct | xF16], each n*256 f16 (== out_size f32 bytes)
    unsigned short* hAct = (unsigned short*)d_out;
    unsigned short* xF   = hAct + (size_t)n * 256;
    float* outF = (float*)d_out;

    char* ws = (char*)d_ws;
    unsigned short* hLin = (unsigned short*)ws;    // n*256 f16 (25.6 MB)
    size_t off  = (size_t)n * 256 * 2;
    off = (off + 255) & ~(size_t)255;
    float* dinv = (float*)(ws + off); off += (size_t)n * 4;
    int*   cnt  = (int*)(ws + off);   off += (size_t)n * 4;
    int*   scn  = (int*)(ws + off);   off += (size_t)n * 4;
    int*   cur  = (int*)(ws + off);   off += (size_t)n * 4;
    int*   bsum = (int*)(ws + off);   off += 4096;
    int*   ssrc = (int*)(ws + off);   off += (size_t)E * 4;
    float* snrm = (float*)(ws + off); off += (size_t)E * 4;
    off = (off + 255) & ~(size_t)255;
    unsigned short* Wsp = (unsigned short*)(ws + off);  // [3][2][256][256] f16
    off += (size_t)3 * 2 * 65536 * 2;

    hipMemsetAsync(cnt, 0, (size_t)n * 4, stream);

    const int eb = (E + 255) / 256;
    const int nb = (n + 255) / 256;  // 196 <= 256 required by scan_add reduce

    prep_wx_kernel<<<48 + 1024, 256, 0, stream>>>(W1, W2, W3, Wsp, x, xF, n * 64);

    hist_kernel<<<eb, 256, 0, stream>>>(dst, E, cnt);
    scan_block_kernel<<<nb, 256, 0, stream>>>(cnt, n, scn, bsum);
    scan_add_dinv_kernel<<<nb, 256, 0, stream>>>(scn, n, bsum, nb, cnt, dinv, cur);
    scatter_kernel<<<eb, 256, 0, stream>>>(src, dst, E, dinv, cur, ssrc, snrm);

    const int gb = ((n + 127) / 128) * 2;  // 782 blocks (swizzled in-kernel)
    const int ab = (n + 3) / 4;

    gemm_f16_kernel<<<gb, 256, 0, stream>>>(xF, Wsp, Wsp + 65536, hLin, n);
    agg_kernel<1, 1><<<ab, 256, 0, stream>>>(hLin, ssrc, snrm, cnt, scn, dinv, b1,
                                             hAct, nullptr, n);
    gemm_f16_kernel<<<gb, 256, 0, stream>>>(hAct, Wsp + 131072, Wsp + 196608, hLin, n);
    agg_kernel<1, 1><<<ab, 256, 0, stream>>>(hLin, ssrc, snrm, cnt, scn, dinv, b2,
                                             hAct, nullptr, n);
    gemm_f16_kernel<<<gb, 256, 0, stream>>>(hAct, Wsp + 262144, Wsp + 327680, hLin, n);
    agg_kernel<0, 0><<<ab, 256, 0, stream>>>(hLin, ssrc, snrm, cnt, scn, dinv, b3,
                                             nullptr, outF, n);
}